// Round 6
// baseline (202.919 us; speedup 1.0000x reference)
//
#include <hip/hip_runtime.h>
#include <math.h>

// Problem constants (from reference)
#define BB 4
#define TT 2048
#define CC 48
#define DD 512
#define LL 16
#define NTR 15
#define NCAND 45
#define WINLEN 19   // int(T/L*0.15)
#define CSW 15
#define CCHALF 7

static __device__ __forceinline__ float wave_reduce_sum(float v) {
    for (int off = 32; off; off >>= 1) v += __shfl_down(v, off);
    return v;
}

// DPP max step
#define DPPMAX(x, ctrl) fmaxf((x), __int_as_float(__builtin_amdgcn_update_dpp( \
    __float_as_int(x), __float_as_int(x), (ctrl), 0xF, 0xF, false)))

// ---------------- Kernel 1: row log-sum-exp only ----------------
__global__ __launch_bounds__(256) void k_lse(const float* __restrict__ fr,
                                             float* __restrict__ lse) {
    int row = blockIdx.x * 4 + (threadIdx.x >> 6);   // 4 rows/block
    int lane = threadIdx.x & 63;
    float xv = (lane < CC) ? fr[(size_t)row * CC + lane] : -INFINITY;
    float m = xv;
    for (int off = 32; off; off >>= 1) m = fmaxf(m, __shfl_down(m, off));
    m = __shfl(m, 0);
    float e = (lane < CC) ? __expf(xv - m) : 0.f;
    float s = wave_reduce_sum(e);
    if (lane == 0) lse[row] = m + __logf(s);
}

// ---------------- Kernel 2: boundary (JS) score, on-the-fly softmax ----------------
// acc = -2*sum_{i<4,c} p_i lp_i  -  sum_{pairs,c} w_ij (p_i+p_j) log m_ij
// score = -2/(81 ln2) * acc ; p=exp(x-lse), lp=x-lse; OOB rows p=lp=0.
__global__ __launch_bounds__(64) void k_score(const float* __restrict__ fr,
                                              const float* __restrict__ lse,
                                              float* __restrict__ score) {
    int row = blockIdx.x;
    int b = row / TT, t = row % TT;
    __shared__ float sp[9][CC];
    __shared__ float slp[9][CC];
    __shared__ float lse_s[9];
    int tid = threadIdx.x;
    if (tid < 9) {
        int r = t - 4 + tid;
        lse_s[tid] = (r >= 0 && r < TT) ? lse[b * TT + r] : 0.f;
    }
    __syncthreads();
    for (int idx = tid; idx < 9 * CC; idx += 64) {
        int i = idx / CC, c = idx - (idx / CC) * CC;
        int r = t - 4 + i;
        float pv = 0.f, lv = 0.f;
        if (r >= 0 && r < TT) {
            float x = fr[((size_t)b * TT + r) * CC + c];
            lv = x - lse_s[i];
            pv = __expf(lv);
        }
        sp[i][c] = pv;
        slp[i][c] = lv;   // 0 when OOB (p=0 -> contributes 0)
    }
    __syncthreads();
    float acc = 0.f;
    // entropy part: rows 0..3, coefficient -2
    for (int idx = tid; idx < 4 * CC; idx += 64) {
        int i = idx / CC, c = idx - (idx / CC) * CC;
        acc += -2.f * sp[i][c] * slp[i][c];
    }
    // pair part
    for (int item = tid; item < 36 * CC; item += 64) {
        int pidx = item / CC, c = item - pidx * CC;
        int i = 0, rem = pidx;
        while (rem >= 8 - i) { rem -= 8 - i; ++i; }
        int j = i + 1 + rem;
        float wgt = ((i < 4) == (j < 4)) ? 1.f : -1.f;
        float pi = sp[i][c], pj = sp[j][c];
        float logm = __logf(0.5f * (pi + pj) + 1e-32f);
        acc -= wgt * (pi + pj) * logm;
    }
    acc = wave_reduce_sum(acc);
    if (tid == 0) {
        const float SC = -2.0f / (81.0f * 0.6931471805599453f);
        score[row] = (t == 0) ? -INFINITY : SC * acc;
    }
}

// ---------------- Kernel 3: pick + cls + DP + backtrack + pse/seg + labels ----------------
__global__ __launch_bounds__(256) void k_pickdp(const float* __restrict__ fr,
                                                const float* __restrict__ lse,
                                                const float* __restrict__ score,
                                                const int* __restrict__ transcript,
                                                int* __restrict__ labels_out,
                                                int* __restrict__ pse,
                                                int* __restrict__ seg_start,
                                                int* __restrict__ seg_end) {
    int b = blockIdx.x;
    __shared__ float s[64 * 33];
    __shared__ int cl[NCAND];
    __shared__ float cost[NTR][NCAND];
    __shared__ int tr_s[LL];
    __shared__ int cand_s[NCAND];
    __shared__ float backup_s[NCAND];
    __shared__ signed char dir_mat[NCAND][32];
    __shared__ int bdy_s[NTR];
    __shared__ int rank_s[LL];
    int tid = threadIdx.x;
    if (tid < LL) tr_s[tid] = transcript[b * LL + tid];
    for (int t = tid; t < TT; t += 256) s[t + (t >> 5)] = score[(size_t)b * TT + t];
    __syncthreads();

    // ---- greedy pick (wave 0, register-resident, DPP reduce) ----
    if (tid < 64) {
        int lane = tid;
        float v[32];
        #pragma unroll
        for (int k = 0; k < 32; ++k) v[k] = s[lane * 33 + k];
        int base = lane << 5;
        for (int it = 0; it < NCAND; ++it) {
            float best = -INFINITY; int bi = 0;
            #pragma unroll
            for (int k = 31; k >= 0; --k)
                if (v[k] >= best) { best = v[k]; bi = k; }
            float m = best;
            m = DPPMAX(m, 0x111); m = DPPMAX(m, 0x112);
            m = DPPMAX(m, 0x114); m = DPPMAX(m, 0x118);
            m = DPPMAX(m, 0x142); m = DPPMAX(m, 0x143);
            float gmax = __int_as_float(__builtin_amdgcn_readlane(__float_as_int(m), 63));
            unsigned long long ball = __ballot(best == gmax);
            int sl = (int)(__ffsll(ball) - 1);
            int mp = __builtin_amdgcn_readlane(base + bi, sl);
            if (lane == 0) cl[it] = mp;
            int llo = mp - WINLEN - base;
            int lhi = mp + WINLEN - base;
            unsigned lowm = (llo <= 0) ? 0xffffffffu : ((llo >= 32) ? 0u : ~((1u << llo) - 1u));
            unsigned him  = (lhi >= 31) ? 0xffffffffu : ((lhi < 0) ? 0u : ((2u << lhi) - 1u));
            unsigned wm = lowm & him;
            #pragma unroll
            for (int k = 0; k < 32; ++k)
                if (wm & (1u << k)) v[k] = -INFINITY;
        }
        // rank-sort (positions distinct)
        if (lane < NCAND) {
            int my = cl[lane];
            int rank = 0;
            for (int i = 0; i < NCAND; ++i) rank += (cl[i] < my) ? 1 : 0;
            cand_s[rank] = my;
        }
    }
    __syncthreads();
    if (tid < NCAND) {
        int cp = cand_s[tid];
        backup_s[tid] = s[cp + (cp >> 5)];
    }
    __syncthreads();

    // ---- cls cost: p on the fly from fr/lse ----
    for (int e = tid; e < NTR * NCAND; e += 256) {
        int j = e / NCAND, ii = e - (e / NCAND) * NCAND;
        int cpos = cand_s[ii];
        int trj = tr_s[j], trj1 = tr_s[j + 1];
        float sum = 0.f;
        for (int k = 0; k < CSW; ++k) {
            int r = cpos - CCHALF + k;
            float a = 0.f, d2 = 0.f;
            if (r >= 0 && r < TT) {
                size_t ro = (size_t)b * TT + r;
                float ls = lse[ro];
                a  = __expf(fr[ro * CC + trj]  - ls);
                d2 = __expf(fr[ro * CC + trj1] - ls);
            }
            sum += ((k < CCHALF) ? 1.f : -1.f) * (a - d2);
        }
        cost[j][ii] = -(sum / 30.f + backup_s[ii]);
    }
    __syncthreads();

    // ---- DP (wave 0, state j = lane j, W=31) ----
    if (tid < 64) {
        int lane = tid;
        float prev = INFINITY;
        if (lane == 0) prev = 0.f;
        if (lane == 1) prev = cost[0][0];
        if (lane < 31) dir_mat[0][lane] = (lane == 1) ? (signed char)1 : (signed char)0;
        for (int ii = 1; ii < NCAND; ++ii) {
            float dm1 = __shfl_up(prev, 1); if (lane < 1) dm1 = INFINITY;
            float dm2 = __shfl_up(prev, 2); if (lane < 2) dm2 = INFINITY;
            int trat = lane >> 1; if (trat > NTR - 1) trat = NTR - 1;
            float c_at = cost[trat][ii];
            float ev = fminf(prev, dm1);
            int ed = (prev < dm1) ? 0 : 1;
            float ov = c_at + fminf(dm1, dm2);
            int od = (dm1 < dm2) ? 1 : 2;
            float nv; int nd;
            if (lane >= 2) {
                if ((lane & 1) == 0) { nv = ev; nd = ed; }
                else { nv = ov; nd = od; }
            } else { nv = INFINITY; nd = 0; }
            if (lane == 0) { nv = (ii < NCAND - NTR) ? 0.f : INFINITY; nd = 0; }
            if (lane == 1) {
                nv = (ii <= NCAND - NTR) ? cost[0][ii] : INFINITY;
                nd = (ii <= NCAND - NTR) ? 1 : 0;
            }
            prev = nv;
            if (lane < 31) dir_mat[ii][lane] = (signed char)nd;
        }
        float v29 = __shfl(prev, 29);
        float v30 = __shfl(prev, 30);
        if (lane == 0) {
            int cur = (v30 < v29) ? 30 : 29;
            for (int ii = NCAND - 1; ii >= 0; --ii) {
                if (cur & 1) bdy_s[cur >> 1] = cand_s[ii];
                cur -= (int)dir_mat[ii][cur];
            }
            int lab[LL];
            for (int i2 = 0; i2 < LL; ++i2) lab[i2] = tr_s[i2];
            for (int a2 = 1; a2 < LL; ++a2) {
                int key = lab[a2]; int b2 = a2 - 1;
                while (b2 >= 0 && lab[b2] > key) { lab[b2 + 1] = lab[b2]; --b2; }
                lab[b2 + 1] = key;
            }
            for (int i2 = 0; i2 < LL; ++i2) labels_out[b * LL + i2] = lab[i2];
            for (int j2 = 0; j2 < LL; ++j2) {
                int r2 = 0;
                for (int l2 = 0; l2 < LL; ++l2) if (lab[l2] == tr_s[j2]) r2 = l2;
                rank_s[j2] = r2;
            }
            // segment ranges per la-row (rank): cnt=j covers [bdy[j-1], bdy[j])
            for (int j2 = 0; j2 < LL; ++j2) {
                int st = (j2 == 0) ? 0 : bdy_s[j2 - 1];
                int en = (j2 == LL - 1) ? TT : bdy_s[j2];
                seg_start[b * LL + rank_s[j2]] = st;
                seg_end[b * LL + rank_s[j2]] = en;
            }
        }
    }
    __syncthreads();
    for (int t = tid; t < TT; t += 256) {
        int cnt = 0;
        for (int j = 0; j < NTR; ++j) cnt += (t >= bdy_s[j]) ? 1 : 0;
        pse[b * TT + t] = tr_s[cnt];
    }
}

// ---------------- Kernel 4: segment feature sums, direct range sum ----------------
// block (l,b): la[b][l] = sum of feat fr-rows in [seg_start, seg_end); 4 waves split rows.
__global__ __launch_bounds__(256) void k_la(const float* __restrict__ feat,
                                            const int* __restrict__ seg_start,
                                            const int* __restrict__ seg_end,
                                            float* __restrict__ la) {
    int l = blockIdx.x, b = blockIdx.y;
    int st = seg_start[b * LL + l], en = seg_end[b * LL + l];
    int wave = threadIdx.x >> 6, lane = threadIdx.x & 63;
    const float* fr = feat + ((size_t)b * (CC + TT) + CC) * DD;
    __shared__ float part[4][DD];
    float4 a0 = {0,0,0,0}, a1 = {0,0,0,0};
    for (int r = st + wave; r < en; r += 4) {
        const float4* p = (const float4*)(fr + (size_t)r * DD);
        float4 v0 = p[lane];          // cols [lane*4, lane*4+4)
        float4 v1 = p[64 + lane];     // cols [256+lane*4, ...)
        a0.x += v0.x; a0.y += v0.y; a0.z += v0.z; a0.w += v0.w;
        a1.x += v1.x; a1.y += v1.y; a1.z += v1.z; a1.w += v1.w;
    }
    ((float4*)part[wave])[lane] = a0;
    ((float4*)part[wave])[64 + lane] = a1;
    __syncthreads();
    float* lar = la + ((size_t)b * LL + l) * DD;
    for (int idx = threadIdx.x; idx < DD; idx += 256)
        lar[idx] = part[0][idx] + part[1][idx] + part[2][idx] + part[3][idx];
}

// ---------------- Kernel 5: glc per (b,l): norms inline + 48 dots + logsumexp ----------------
__global__ __launch_bounds__(256) void k_glc(const float* __restrict__ feat,
                                             const float* __restrict__ la,
                                             const int* __restrict__ labels,
                                             float* __restrict__ terms) {
    int l = blockIdx.x, b = blockIdx.y;
    __shared__ float la_s[DD];
    __shared__ float sim_s[CC];
    __shared__ float red[4];
    __shared__ float s_inv_nla;
    int tid = threadIdx.x;
    int wave = tid >> 6, lane = tid & 63;
    const float* lar = la + ((size_t)b * LL + l) * DD;
    float2 lv = ((const float2*)lar)[tid];
    ((float2*)la_s)[tid] = lv;
    float ss = lv.x * lv.x + lv.y * lv.y;
    ss = wave_reduce_sum(ss);
    if (lane == 0) red[wave] = ss;
    __syncthreads();
    if (tid == 0)
        s_inv_nla = 10.0f / fmaxf(sqrtf(red[0] + red[1] + red[2] + red[3]), 1e-12f);
    __syncthreads();
    for (int c = wave; c < CC; c += 4) {
        const float4* tr = (const float4*)(feat + ((size_t)b * (CC + TT) + c) * DD);
        const float4* ls = (const float4*)la_s;
        float dot = 0.f, vv = 0.f;
        for (int j = lane; j < DD / 4; j += 64) {
            float4 a = ls[j]; float4 v = tr[j];
            dot += a.x * v.x + a.y * v.y + a.z * v.z + a.w * v.w;
            vv  += v.x * v.x + v.y * v.y + v.z * v.z + v.w * v.w;
        }
        dot = wave_reduce_sum(dot);
        vv  = wave_reduce_sum(vv);
        if (lane == 0)
            sim_s[c] = dot * s_inv_nla / fmaxf(sqrtf(vv), 1e-12f);
    }
    __syncthreads();
    if (tid == 0) {
        float mx = -INFINITY;
        for (int c = 0; c < CC; ++c) mx = fmaxf(mx, sim_s[c]);
        float se = 0.f;
        for (int c = 0; c < CC; ++c) se += expf(sim_s[c] - mx);
        int lab = labels[b * LL + l];
        terms[b * LL + l] = (mx + logf(se)) - sim_s[lab];
    }
}

// ---------------- Kernel 6: fr CE partials (8 blocks, direct writes) ----------------
__global__ __launch_bounds__(256) void k_fr(const float* __restrict__ fr_logit,
                                            const float* __restrict__ lse,
                                            const int* __restrict__ pse,
                                            float* __restrict__ fr_part) {
    __shared__ float red[4];
    int tid = threadIdx.x;
    float acc = 0.f;
    for (int k = 0; k < 4; ++k) {
        int i = blockIdx.x * 1024 + k * 256 + tid;
        int p = pse[i];
        acc += lse[i] - fr_logit[(size_t)i * CC + p];
    }
    acc = wave_reduce_sum(acc);
    if ((tid & 63) == 0) red[tid >> 6] = acc;
    __syncthreads();
    if (tid == 0) fr_part[blockIdx.x] = red[0] + red[1] + red[2] + red[3];
}

// ---------------- Kernel 7: combine ----------------
__global__ __launch_bounds__(256) void k_combine(const float* __restrict__ tok_logit,
                                                 const float* __restrict__ vid,
                                                 const float* __restrict__ fr_part,
                                                 const float* __restrict__ terms,
                                                 float* __restrict__ out) {
    int tid = threadIdx.x;
    __shared__ float red[4];
    float acc = 0.f;
    if (tid < BB * CC) {
        float x = tok_logit[tid], y = vid[tid];
        float lsp = fminf(x, 0.f) - log1pf(expf(-fabsf(x)));
        float lsn = fminf(-x, 0.f) - log1pf(expf(-fabsf(x)));
        acc = -(y * lsp + (1.f - y) * lsn);
    }
    float w = wave_reduce_sum(acc);
    if ((tid & 63) == 0) red[tid >> 6] = w;
    __syncthreads();
    if (tid == 0) {
        float s_tok = (red[0] + red[1] + red[2] + red[3]) / (float)(BB * CC);
        float sfr = 0.f;
        for (int i = 0; i < 8; ++i) sfr += fr_part[i];
        float s_fr = sfr / (float)(BB * TT);
        float g = 0.f;
        for (int i = 0; i < BB * LL; ++i) g += terms[i];
        float glc = g / (float)(BB * LL);
        out[0] = s_tok + s_fr + 0.1f * glc;
    }
}

extern "C" void kernel_launch(void* const* d_in, const int* in_sizes, int n_in,
                              void* d_out, int out_size, void* d_ws, size_t ws_size,
                              hipStream_t stream) {
    (void)in_sizes; (void)n_in; (void)out_size; (void)ws_size;
    // input order: epoch, tok_logit, fr_logit, mask, transcript, vid_multi_hot, feat
    const float* tok_logit  = (const float*)d_in[1];
    const float* fr_logit   = (const float*)d_in[2];
    const int*   transcript = (const int*)d_in[4];
    const float* vid        = (const float*)d_in[5];
    const float* feat       = (const float*)d_in[6];

    char* ws = (char*)d_ws;
    float* lse     = (float*)(ws + 0);        // B*T        (32768 B)
    float* score   = (float*)(ws + 32768);    // B*T        (32768 B)
    float* la      = (float*)(ws + 65536);    // B*L*D      (131072 B)
    float* terms   = (float*)(ws + 196608);   // B*L
    float* fr_part = (float*)(ws + 196864);   // 8
    int*   labels  = (int*)(ws + 197120);     // B*L
    int*   pse     = (int*)(ws + 197376);     // B*T        (32768 B)
    int*   seg_st  = (int*)(ws + 230144);     // B*L
    int*   seg_en  = (int*)(ws + 230400);     // B*L
    float* out     = (float*)d_out;

    k_lse<<<BB * TT / 4, 256, 0, stream>>>(fr_logit, lse);
    k_score<<<BB * TT, 64, 0, stream>>>(fr_logit, lse, score);
    k_pickdp<<<BB, 256, 0, stream>>>(fr_logit, lse, score, transcript,
                                     labels, pse, seg_st, seg_en);
    k_fr<<<8, 256, 0, stream>>>(fr_logit, lse, pse, fr_part);
    k_la<<<dim3(LL, BB), 256, 0, stream>>>(feat, seg_st, seg_en, la);
    k_glc<<<dim3(LL, BB), 256, 0, stream>>>(feat, la, labels, terms);
    k_combine<<<1, 256, 0, stream>>>(tok_logit, vid, fr_part, terms, out);
}

// Round 7
// 199.360 us; speedup vs baseline: 1.0179x; 1.0179x over previous
//
#include <hip/hip_runtime.h>
#include <math.h>

// Problem constants (from reference)
#define BB 4
#define TT 2048
#define CC 48
#define DD 512
#define LL 16
#define NTR 15
#define NCAND 45
#define WINLEN 19   // int(T/L*0.15)
#define CSW 15
#define CCHALF 7

static __device__ __forceinline__ float wave_reduce_sum(float v) {
    for (int off = 32; off; off >>= 1) v += __shfl_down(v, off);
    return v;
}

// DPP max step
#define DPPMAX(x, ctrl) fmaxf((x), __int_as_float(__builtin_amdgcn_update_dpp( \
    __float_as_int(x), __float_as_int(x), (ctrl), 0xF, 0xF, false)))

// ---------------- Kernel 1: row log-sum-exp only ----------------
__global__ __launch_bounds__(256) void k_lse(const float* __restrict__ fr,
                                             float* __restrict__ lse) {
    int row = blockIdx.x * 4 + (threadIdx.x >> 6);   // 4 rows/block
    int lane = threadIdx.x & 63;
    float xv = (lane < CC) ? fr[(size_t)row * CC + lane] : -INFINITY;
    float m = xv;
    for (int off = 32; off; off >>= 1) m = fmaxf(m, __shfl_down(m, off));
    m = __shfl(m, 0);
    float e = (lane < CC) ? __expf(xv - m) : 0.f;
    float s = wave_reduce_sum(e);
    if (lane == 0) lse[row] = m + __logf(s);
}

// ---------------- Kernel 2: boundary (JS) score, on-the-fly softmax ----------------
__global__ __launch_bounds__(64) void k_score(const float* __restrict__ fr,
                                              const float* __restrict__ lse,
                                              float* __restrict__ score) {
    int row = blockIdx.x;
    int b = row / TT, t = row % TT;
    __shared__ float sp[9][CC];
    __shared__ float slp[9][CC];
    __shared__ float lse_s[9];
    int tid = threadIdx.x;
    if (tid < 9) {
        int r = t - 4 + tid;
        lse_s[tid] = (r >= 0 && r < TT) ? lse[b * TT + r] : 0.f;
    }
    __syncthreads();
    for (int idx = tid; idx < 9 * CC; idx += 64) {
        int i = idx / CC, c = idx - (idx / CC) * CC;
        int r = t - 4 + i;
        float pv = 0.f, lv = 0.f;
        if (r >= 0 && r < TT) {
            float x = fr[((size_t)b * TT + r) * CC + c];
            lv = x - lse_s[i];
            pv = __expf(lv);
        }
        sp[i][c] = pv;
        slp[i][c] = lv;
    }
    __syncthreads();
    float acc = 0.f;
    for (int idx = tid; idx < 4 * CC; idx += 64) {
        int i = idx / CC, c = idx - (idx / CC) * CC;
        acc += -2.f * sp[i][c] * slp[i][c];
    }
    for (int item = tid; item < 36 * CC; item += 64) {
        int pidx = item / CC, c = item - pidx * CC;
        int i = 0, rem = pidx;
        while (rem >= 8 - i) { rem -= 8 - i; ++i; }
        int j = i + 1 + rem;
        float wgt = ((i < 4) == (j < 4)) ? 1.f : -1.f;
        float pi = sp[i][c], pj = sp[j][c];
        float logm = __logf(0.5f * (pi + pj) + 1e-32f);
        acc -= wgt * (pi + pj) * logm;
    }
    acc = wave_reduce_sum(acc);
    if (tid == 0) {
        const float SC = -2.0f / (81.0f * 0.6931471805599453f);
        score[row] = (t == 0) ? -INFINITY : SC * acc;
    }
}

// ---------------- Kernel 3: pick + cls + DP + backtrack + seg + labels + frCE ----------------
__global__ __launch_bounds__(256) void k_pickdp(const float* __restrict__ fr,
                                                const float* __restrict__ lse,
                                                const float* __restrict__ score,
                                                const int* __restrict__ transcript,
                                                int* __restrict__ labels_out,
                                                int* __restrict__ seg_start,
                                                int* __restrict__ seg_end,
                                                float* __restrict__ fr_part) {
    int b = blockIdx.x;
    __shared__ int cl[NCAND];
    __shared__ float cost[NTR][NCAND];
    __shared__ int tr_s[LL];
    __shared__ int cand_s[NCAND];
    __shared__ float backup_s[NCAND];
    __shared__ signed char dir_mat[NCAND][32];
    __shared__ int bdy_s[NTR];
    __shared__ int rank_s[LL];
    __shared__ float rv[2][4];
    __shared__ int rp[2][4];
    __shared__ float redf[4];
    int tid = threadIdx.x;
    int wave = tid >> 6, lane = tid & 63;
    if (tid < LL) tr_s[tid] = transcript[b * LL + tid];

    // ---- greedy pick: 8 elements/thread, register-resident ----
    float v[8];
    {
        const float4* sp4 = (const float4*)(score + (size_t)b * TT);
        float4 va = sp4[2 * tid], vb = sp4[2 * tid + 1];
        v[0] = va.x; v[1] = va.y; v[2] = va.z; v[3] = va.w;
        v[4] = vb.x; v[5] = vb.y; v[6] = vb.z; v[7] = vb.w;
    }
    for (int it = 0; it < NCAND; ++it) {
        float best = -INFINITY; int bi = 0;
        #pragma unroll
        for (int k = 7; k >= 0; --k)
            if (v[k] >= best) { best = v[k]; bi = k; }
        int pos = tid * 8 + bi;
        float m = best;
        m = DPPMAX(m, 0x111); m = DPPMAX(m, 0x112);
        m = DPPMAX(m, 0x114); m = DPPMAX(m, 0x118);
        m = DPPMAX(m, 0x142); m = DPPMAX(m, 0x143);
        float wmax = __int_as_float(__builtin_amdgcn_readlane(__float_as_int(m), 63));
        unsigned long long ball = __ballot(best == wmax);
        int sl = (int)(__ffsll((long long)ball) - 1);
        int wpos = __builtin_amdgcn_readlane(pos, sl);
        if (lane == 0) { rv[it & 1][wave] = wmax; rp[it & 1][wave] = wpos; }
        __syncthreads();
        float bvv = -INFINITY; int mp = 0x7fffffff;
        #pragma unroll
        for (int w = 0; w < 4; ++w) {
            float vv = rv[it & 1][w]; int pp = rp[it & 1][w];
            if (vv > bvv || (vv == bvv && pp < mp)) { bvv = vv; mp = pp; }
        }
        if (tid == 0) cl[it] = mp;
        int lo = mp - WINLEN, hi = mp + WINLEN;
        #pragma unroll
        for (int k = 0; k < 8; ++k) {
            int t = tid * 8 + k;
            if (t >= lo && t <= hi) v[k] = -INFINITY;
        }
    }
    __syncthreads();
    // rank-sort (positions distinct)
    if (tid < NCAND) {
        int my = cl[tid];
        int rank = 0;
        for (int i = 0; i < NCAND; ++i) rank += (cl[i] < my) ? 1 : 0;
        cand_s[rank] = my;
    }
    __syncthreads();
    if (tid < NCAND) backup_s[tid] = score[(size_t)b * TT + cand_s[tid]];
    __syncthreads();

    // ---- cls cost: p on the fly from fr/lse ----
    for (int e = tid; e < NTR * NCAND; e += 256) {
        int j = e / NCAND, ii = e - (e / NCAND) * NCAND;
        int cpos = cand_s[ii];
        int trj = tr_s[j], trj1 = tr_s[j + 1];
        float sum = 0.f;
        for (int k = 0; k < CSW; ++k) {
            int r = cpos - CCHALF + k;
            float a = 0.f, d2 = 0.f;
            if (r >= 0 && r < TT) {
                size_t ro = (size_t)b * TT + r;
                float ls = lse[ro];
                a  = __expf(fr[ro * CC + trj]  - ls);
                d2 = __expf(fr[ro * CC + trj1] - ls);
            }
            sum += ((k < CCHALF) ? 1.f : -1.f) * (a - d2);
        }
        cost[j][ii] = -(sum / 30.f + backup_s[ii]);
    }
    __syncthreads();

    // ---- DP (wave 0, state j = lane j, W=31) ----
    if (tid < 64) {
        float prev = INFINITY;
        if (tid == 0) prev = 0.f;
        if (tid == 1) prev = cost[0][0];
        if (tid < 31) dir_mat[0][tid] = (tid == 1) ? (signed char)1 : (signed char)0;
        for (int ii = 1; ii < NCAND; ++ii) {
            float dm1 = __shfl_up(prev, 1); if (tid < 1) dm1 = INFINITY;
            float dm2 = __shfl_up(prev, 2); if (tid < 2) dm2 = INFINITY;
            int trat = tid >> 1; if (trat > NTR - 1) trat = NTR - 1;
            float c_at = cost[trat][ii];
            float ev = fminf(prev, dm1);
            int ed = (prev < dm1) ? 0 : 1;
            float ov = c_at + fminf(dm1, dm2);
            int od = (dm1 < dm2) ? 1 : 2;
            float nv; int nd;
            if (tid >= 2) {
                if ((tid & 1) == 0) { nv = ev; nd = ed; }
                else { nv = ov; nd = od; }
            } else { nv = INFINITY; nd = 0; }
            if (tid == 0) { nv = (ii < NCAND - NTR) ? 0.f : INFINITY; nd = 0; }
            if (tid == 1) {
                nv = (ii <= NCAND - NTR) ? cost[0][ii] : INFINITY;
                nd = (ii <= NCAND - NTR) ? 1 : 0;
            }
            prev = nv;
            if (tid < 31) dir_mat[ii][tid] = (signed char)nd;
        }
        float v29 = __shfl(prev, 29);
        float v30 = __shfl(prev, 30);
        if (tid == 0) {
            int cur = (v30 < v29) ? 30 : 29;
            for (int ii = NCAND - 1; ii >= 0; --ii) {
                if (cur & 1) bdy_s[cur >> 1] = cand_s[ii];
                cur -= (int)dir_mat[ii][cur];
            }
            int lab[LL];
            for (int i2 = 0; i2 < LL; ++i2) lab[i2] = tr_s[i2];
            for (int a2 = 1; a2 < LL; ++a2) {
                int key = lab[a2]; int b2 = a2 - 1;
                while (b2 >= 0 && lab[b2] > key) { lab[b2 + 1] = lab[b2]; --b2; }
                lab[b2 + 1] = key;
            }
            for (int i2 = 0; i2 < LL; ++i2) labels_out[b * LL + i2] = lab[i2];
            for (int j2 = 0; j2 < LL; ++j2) {
                int r2 = 0;
                for (int l2 = 0; l2 < LL; ++l2) if (lab[l2] == tr_s[j2]) r2 = l2;
                rank_s[j2] = r2;
            }
            for (int j2 = 0; j2 < LL; ++j2) {
                int st = (j2 == 0) ? 0 : bdy_s[j2 - 1];
                int en = (j2 == LL - 1) ? TT : bdy_s[j2];
                seg_start[b * LL + rank_s[j2]] = st;
                seg_end[b * LL + rank_s[j2]] = en;
            }
        }
    }
    __syncthreads();

    // ---- fr CE partial for this batch (pse computed inline, never stored) ----
    float facc = 0.f;
    for (int t = tid; t < TT; t += 256) {
        int cnt = 0;
        for (int j = 0; j < NTR; ++j) cnt += (t >= bdy_s[j]) ? 1 : 0;
        int pv = tr_s[cnt];
        size_t ro = (size_t)b * TT + t;
        facc += lse[ro] - fr[ro * CC + pv];
    }
    facc = wave_reduce_sum(facc);
    if (lane == 0) redf[wave] = facc;
    __syncthreads();
    if (tid == 0) fr_part[b] = redf[0] + redf[1] + redf[2] + redf[3];
}

// ---------------- Kernel 4: la range-sum (LDS) + glc dots + logsumexp ----------------
__global__ __launch_bounds__(256) void k_laglc(const float* __restrict__ feat,
                                               const int* __restrict__ seg_start,
                                               const int* __restrict__ seg_end,
                                               const int* __restrict__ labels,
                                               float* __restrict__ terms) {
    int l = blockIdx.x, b = blockIdx.y;
    int st = seg_start[b * LL + l], en = seg_end[b * LL + l];
    int tid = threadIdx.x;
    int wave = tid >> 6, lane = tid & 63;
    const float* frf = feat + ((size_t)b * (CC + TT) + CC) * DD;
    __shared__ float part[4][DD];      // 8 KB
    __shared__ float la_s[DD];
    __shared__ float sim_s[CC];
    __shared__ float red[4];
    __shared__ float s_inv_nla;
    float4 a0 = {0,0,0,0}, a1 = {0,0,0,0};
    for (int r = st + wave; r < en; r += 4) {
        const float4* p = (const float4*)(frf + (size_t)r * DD);
        float4 v0 = p[lane];
        float4 v1 = p[64 + lane];
        a0.x += v0.x; a0.y += v0.y; a0.z += v0.z; a0.w += v0.w;
        a1.x += v1.x; a1.y += v1.y; a1.z += v1.z; a1.w += v1.w;
    }
    ((float4*)part[wave])[lane] = a0;
    ((float4*)part[wave])[64 + lane] = a1;
    __syncthreads();
    float ssl = 0.f;
    for (int idx = tid; idx < DD; idx += 256) {
        float s = part[0][idx] + part[1][idx] + part[2][idx] + part[3][idx];
        la_s[idx] = s;
        ssl += s * s;
    }
    ssl = wave_reduce_sum(ssl);
    if (lane == 0) red[wave] = ssl;
    __syncthreads();
    if (tid == 0)
        s_inv_nla = 10.0f / fmaxf(sqrtf(red[0] + red[1] + red[2] + red[3]), 1e-12f);
    __syncthreads();
    for (int c = wave; c < CC; c += 4) {
        const float4* tr = (const float4*)(feat + ((size_t)b * (CC + TT) + c) * DD);
        const float4* ls = (const float4*)la_s;
        float dot = 0.f, vv = 0.f;
        for (int j = lane; j < DD / 4; j += 64) {
            float4 a = ls[j]; float4 w = tr[j];
            dot += a.x * w.x + a.y * w.y + a.z * w.z + a.w * w.w;
            vv  += w.x * w.x + w.y * w.y + w.z * w.z + w.w * w.w;
        }
        dot = wave_reduce_sum(dot);
        vv  = wave_reduce_sum(vv);
        if (lane == 0)
            sim_s[c] = dot * s_inv_nla / fmaxf(sqrtf(vv), 1e-12f);
    }
    __syncthreads();
    if (tid == 0) {
        float mx = -INFINITY;
        for (int c = 0; c < CC; ++c) mx = fmaxf(mx, sim_s[c]);
        float se = 0.f;
        for (int c = 0; c < CC; ++c) se += expf(sim_s[c] - mx);
        int lab = labels[b * LL + l];
        terms[b * LL + l] = (mx + logf(se)) - sim_s[lab];
    }
}

// ---------------- Kernel 5: combine ----------------
__global__ __launch_bounds__(256) void k_combine(const float* __restrict__ tok_logit,
                                                 const float* __restrict__ vid,
                                                 const float* __restrict__ fr_part,
                                                 const float* __restrict__ terms,
                                                 float* __restrict__ out) {
    int tid = threadIdx.x;
    __shared__ float red[4];
    float acc = 0.f;
    if (tid < BB * CC) {
        float x = tok_logit[tid], y = vid[tid];
        float lsp = fminf(x, 0.f) - log1pf(expf(-fabsf(x)));
        float lsn = fminf(-x, 0.f) - log1pf(expf(-fabsf(x)));
        acc = -(y * lsp + (1.f - y) * lsn);
    }
    float w = wave_reduce_sum(acc);
    if ((tid & 63) == 0) red[tid >> 6] = w;
    __syncthreads();
    if (tid == 0) {
        float s_tok = (red[0] + red[1] + red[2] + red[3]) / (float)(BB * CC);
        float sfr = fr_part[0] + fr_part[1] + fr_part[2] + fr_part[3];
        float s_fr = sfr / (float)(BB * TT);
        float g = 0.f;
        for (int i = 0; i < BB * LL; ++i) g += terms[i];
        float glc = g / (float)(BB * LL);
        out[0] = s_tok + s_fr + 0.1f * glc;
    }
}

extern "C" void kernel_launch(void* const* d_in, const int* in_sizes, int n_in,
                              void* d_out, int out_size, void* d_ws, size_t ws_size,
                              hipStream_t stream) {
    (void)in_sizes; (void)n_in; (void)out_size; (void)ws_size;
    // input order: epoch, tok_logit, fr_logit, mask, transcript, vid_multi_hot, feat
    const float* tok_logit  = (const float*)d_in[1];
    const float* fr_logit   = (const float*)d_in[2];
    const int*   transcript = (const int*)d_in[4];
    const float* vid        = (const float*)d_in[5];
    const float* feat       = (const float*)d_in[6];

    char* ws = (char*)d_ws;
    float* lse     = (float*)(ws + 0);        // B*T (32768 B)
    float* score   = (float*)(ws + 32768);    // B*T (32768 B)
    float* terms   = (float*)(ws + 65536);    // B*L
    float* fr_part = (float*)(ws + 65792);    // 4
    int*   labels  = (int*)(ws + 66048);      // B*L
    int*   seg_st  = (int*)(ws + 66304);      // B*L
    int*   seg_en  = (int*)(ws + 66560);      // B*L
    float* out     = (float*)d_out;

    k_lse<<<BB * TT / 4, 256, 0, stream>>>(fr_logit, lse);
    k_score<<<BB * TT, 64, 0, stream>>>(fr_logit, lse, score);
    k_pickdp<<<BB, 256, 0, stream>>>(fr_logit, lse, score, transcript,
                                     labels, seg_st, seg_en, fr_part);
    k_laglc<<<dim3(LL, BB), 256, 0, stream>>>(feat, seg_st, seg_en, labels, terms);
    k_combine<<<1, 256, 0, stream>>>(tok_logit, vid, fr_part, terms, out);
}

// Round 8
// 171.283 us; speedup vs baseline: 1.1847x; 1.1639x over previous
//
#include <hip/hip_runtime.h>
#include <math.h>

// Problem constants (from reference)
#define BB 4
#define TT 2048
#define CC 48
#define DD 512
#define LL 16
#define NTR 15
#define NCAND 45
#define WINLEN 19   // int(T/L*0.15)
#define CSW 15
#define CCHALF 7

static __device__ __forceinline__ float wave_reduce_sum(float v) {
    for (int off = 32; off; off >>= 1) v += __shfl_down(v, off);
    return v;
}

// DPP max step
#define DPPMAX(x, ctrl) fmaxf((x), __int_as_float(__builtin_amdgcn_update_dpp( \
    __float_as_int(x), __float_as_int(x), (ctrl), 0xF, 0xF, false)))

// ---------------- Kernel 1: row log-sum-exp only ----------------
__global__ __launch_bounds__(256) void k_lse(const float* __restrict__ fr,
                                             float* __restrict__ lse) {
    int row = blockIdx.x * 4 + (threadIdx.x >> 6);   // 4 rows/block
    int lane = threadIdx.x & 63;
    float xv = (lane < CC) ? fr[(size_t)row * CC + lane] : -INFINITY;
    float m = xv;
    for (int off = 32; off; off >>= 1) m = fmaxf(m, __shfl_down(m, off));
    m = __shfl(m, 0);
    float e = (lane < CC) ? __expf(xv - m) : 0.f;
    float s = wave_reduce_sum(e);
    if (lane == 0) lse[row] = m + __logf(s);
}

// ---------------- Kernel 2: boundary (JS) score, on-the-fly softmax ----------------
__global__ __launch_bounds__(64) void k_score(const float* __restrict__ fr,
                                              const float* __restrict__ lse,
                                              float* __restrict__ score) {
    int row = blockIdx.x;
    int b = row / TT, t = row % TT;
    __shared__ float sp[9][CC];
    __shared__ float slp[9][CC];
    __shared__ float lse_s[9];
    int tid = threadIdx.x;
    if (tid < 9) {
        int r = t - 4 + tid;
        lse_s[tid] = (r >= 0 && r < TT) ? lse[b * TT + r] : 0.f;
    }
    __syncthreads();
    for (int idx = tid; idx < 9 * CC; idx += 64) {
        int i = idx / CC, c = idx - (idx / CC) * CC;
        int r = t - 4 + i;
        float pv = 0.f, lv = 0.f;
        if (r >= 0 && r < TT) {
            float x = fr[((size_t)b * TT + r) * CC + c];
            lv = x - lse_s[i];
            pv = __expf(lv);
        }
        sp[i][c] = pv;
        slp[i][c] = lv;
    }
    __syncthreads();
    float acc = 0.f;
    for (int idx = tid; idx < 4 * CC; idx += 64) {
        int i = idx / CC, c = idx - (idx / CC) * CC;
        acc += -2.f * sp[i][c] * slp[i][c];
    }
    for (int item = tid; item < 36 * CC; item += 64) {
        int pidx = item / CC, c = item - pidx * CC;
        int i = 0, rem = pidx;
        while (rem >= 8 - i) { rem -= 8 - i; ++i; }
        int j = i + 1 + rem;
        float wgt = ((i < 4) == (j < 4)) ? 1.f : -1.f;
        float pi = sp[i][c], pj = sp[j][c];
        float logm = __logf(0.5f * (pi + pj) + 1e-32f);
        acc -= wgt * (pi + pj) * logm;
    }
    acc = wave_reduce_sum(acc);
    if (tid == 0) {
        const float SC = -2.0f / (81.0f * 0.6931471805599453f);
        score[row] = (t == 0) ? -INFINITY : SC * acc;
    }
}

// ---------------- Kernel 3: pick + cls + DP + backtrack + rank + frCE + la-zero ----------------
__global__ __launch_bounds__(256) void k_pickdp(const float* __restrict__ fr,
                                                const float* __restrict__ lse,
                                                const float* __restrict__ score,
                                                const int* __restrict__ transcript,
                                                int* __restrict__ labels_out,
                                                int* __restrict__ rowmap,
                                                float* __restrict__ fr_part,
                                                float* __restrict__ la) {
    int b = blockIdx.x;
    __shared__ int cl[NCAND];
    __shared__ float cost[NTR][NCAND];
    __shared__ int tr_s[LL];
    __shared__ int cand_s[NCAND];
    __shared__ float backup_s[NCAND];
    __shared__ signed char dir_mat[NCAND][32];
    __shared__ int bdy_s[NTR];
    __shared__ int rank_s[LL];
    __shared__ float rv[2][4];
    __shared__ int rp[2][4];
    __shared__ float redf[4];
    int tid = threadIdx.x;
    int wave = tid >> 6, lane = tid & 63;
    if (tid < LL) tr_s[tid] = transcript[b * LL + tid];

    // zero la for this batch (consumed later by k_la atomics)
    {
        float4 z = {0.f, 0.f, 0.f, 0.f};
        float4* lz = (float4*)(la + (size_t)b * LL * DD);
        #pragma unroll
        for (int i = 0; i < LL * DD / 4 / 256; ++i) lz[i * 256 + tid] = z;
    }

    // ---- greedy pick: 8 elements/thread, register-resident ----
    float v[8];
    {
        const float4* sp4 = (const float4*)(score + (size_t)b * TT);
        float4 va = sp4[2 * tid], vb = sp4[2 * tid + 1];
        v[0] = va.x; v[1] = va.y; v[2] = va.z; v[3] = va.w;
        v[4] = vb.x; v[5] = vb.y; v[6] = vb.z; v[7] = vb.w;
    }
    for (int it = 0; it < NCAND; ++it) {
        float best = -INFINITY; int bi = 0;
        #pragma unroll
        for (int k = 7; k >= 0; --k)
            if (v[k] >= best) { best = v[k]; bi = k; }
        int pos = tid * 8 + bi;
        float m = best;
        m = DPPMAX(m, 0x111); m = DPPMAX(m, 0x112);
        m = DPPMAX(m, 0x114); m = DPPMAX(m, 0x118);
        m = DPPMAX(m, 0x142); m = DPPMAX(m, 0x143);
        float wmax = __int_as_float(__builtin_amdgcn_readlane(__float_as_int(m), 63));
        unsigned long long ball = __ballot(best == wmax);
        int sl = (int)(__ffsll((long long)ball) - 1);
        int wpos = __builtin_amdgcn_readlane(pos, sl);
        if (lane == 0) { rv[it & 1][wave] = wmax; rp[it & 1][wave] = wpos; }
        __syncthreads();
        float bvv = -INFINITY; int mp = 0x7fffffff;
        #pragma unroll
        for (int w = 0; w < 4; ++w) {
            float vv = rv[it & 1][w]; int pp = rp[it & 1][w];
            if (vv > bvv || (vv == bvv && pp < mp)) { bvv = vv; mp = pp; }
        }
        if (tid == 0) cl[it] = mp;
        int lo = mp - WINLEN, hi = mp + WINLEN;
        #pragma unroll
        for (int k = 0; k < 8; ++k) {
            int t = tid * 8 + k;
            if (t >= lo && t <= hi) v[k] = -INFINITY;
        }
    }
    __syncthreads();
    // rank-sort (positions distinct)
    if (tid < NCAND) {
        int my = cl[tid];
        int rank = 0;
        for (int i = 0; i < NCAND; ++i) rank += (cl[i] < my) ? 1 : 0;
        cand_s[rank] = my;
    }
    __syncthreads();
    if (tid < NCAND) backup_s[tid] = score[(size_t)b * TT + cand_s[tid]];
    __syncthreads();

    // ---- cls cost: p on the fly from fr/lse ----
    for (int e = tid; e < NTR * NCAND; e += 256) {
        int j = e / NCAND, ii = e - (e / NCAND) * NCAND;
        int cpos = cand_s[ii];
        int trj = tr_s[j], trj1 = tr_s[j + 1];
        float sum = 0.f;
        #pragma unroll
        for (int k = 0; k < CSW; ++k) {
            int r = cpos - CCHALF + k;
            float a = 0.f, d2 = 0.f;
            if (r >= 0 && r < TT) {
                size_t ro = (size_t)b * TT + r;
                float ls = lse[ro];
                a  = __expf(fr[ro * CC + trj]  - ls);
                d2 = __expf(fr[ro * CC + trj1] - ls);
            }
            sum += ((k < CCHALF) ? 1.f : -1.f) * (a - d2);
        }
        cost[j][ii] = -(sum / 30.f + backup_s[ii]);
    }
    __syncthreads();

    // ---- DP (wave 0, state j = lane j, W=31) ----
    if (tid < 64) {
        float prev = INFINITY;
        if (tid == 0) prev = 0.f;
        if (tid == 1) prev = cost[0][0];
        if (tid < 31) dir_mat[0][tid] = (tid == 1) ? (signed char)1 : (signed char)0;
        for (int ii = 1; ii < NCAND; ++ii) {
            float dm1 = __shfl_up(prev, 1); if (tid < 1) dm1 = INFINITY;
            float dm2 = __shfl_up(prev, 2); if (tid < 2) dm2 = INFINITY;
            int trat = tid >> 1; if (trat > NTR - 1) trat = NTR - 1;
            float c_at = cost[trat][ii];
            float ev = fminf(prev, dm1);
            int ed = (prev < dm1) ? 0 : 1;
            float ov = c_at + fminf(dm1, dm2);
            int od = (dm1 < dm2) ? 1 : 2;
            float nv; int nd;
            if (tid >= 2) {
                if ((tid & 1) == 0) { nv = ev; nd = ed; }
                else { nv = ov; nd = od; }
            } else { nv = INFINITY; nd = 0; }
            if (tid == 0) { nv = (ii < NCAND - NTR) ? 0.f : INFINITY; nd = 0; }
            if (tid == 1) {
                nv = (ii <= NCAND - NTR) ? cost[0][ii] : INFINITY;
                nd = (ii <= NCAND - NTR) ? 1 : 0;
            }
            prev = nv;
            if (tid < 31) dir_mat[ii][tid] = (signed char)nd;
        }
        float v29 = __shfl(prev, 29);
        float v30 = __shfl(prev, 30);
        if (tid == 0) {
            int cur = (v30 < v29) ? 30 : 29;
            for (int ii = NCAND - 1; ii >= 0; --ii) {
                if (cur & 1) bdy_s[cur >> 1] = cand_s[ii];
                cur -= (int)dir_mat[ii][cur];
            }
        }
    }
    __syncthreads();

    // ---- parallel rank (transcript values distinct): no sort, no scratch ----
    if (tid < LL) {
        int myv = tr_s[tid];
        int r2 = 0;
        #pragma unroll
        for (int l2 = 0; l2 < LL; ++l2) r2 += (tr_s[l2] < myv) ? 1 : 0;
        rank_s[tid] = r2;
        labels_out[b * LL + r2] = myv;   // sorted scatter
    }
    __syncthreads();

    // ---- fr CE partial + rowmap (pse inline) ----
    float facc = 0.f;
    for (int t = tid; t < TT; t += 256) {
        int cnt = 0;
        #pragma unroll
        for (int j = 0; j < NTR; ++j) cnt += (t >= bdy_s[j]) ? 1 : 0;
        int pv = tr_s[cnt];
        rowmap[b * TT + t] = rank_s[cnt];
        size_t ro = (size_t)b * TT + t;
        facc += lse[ro] - fr[ro * CC + pv];
    }
    facc = wave_reduce_sum(facc);
    if (lane == 0) redf[wave] = facc;
    __syncthreads();
    if (tid == 0) fr_part[b] = redf[0] + redf[1] + redf[2] + redf[3];
}

// ---------------- Kernel 4: segment feature sums, tile-scatter (atomics) ----------------
__global__ __launch_bounds__(256) void k_la(const float* __restrict__ feat,
                                            const int* __restrict__ rowmap,
                                            float* __restrict__ la) {
    int b = blockIdx.y;
    int t0 = blockIdx.x * 32;
    int tid = threadIdx.x;
    const float* frf = feat + ((size_t)b * (CC + TT) + CC) * DD;
    __shared__ int rm[32];
    if (tid < 32) rm[tid] = rowmap[b * TT + t0 + tid];
    __syncthreads();
    float ax = 0.f, ay = 0.f;
    int cur = rm[0];
    for (int k = 0; k < 32; ++k) {
        int r = rm[k];
        if (r != cur) {   // block-uniform branch
            float* dst = la + ((size_t)b * LL + cur) * DD + tid * 2;
            atomicAdd(dst, ax);
            atomicAdd(dst + 1, ay);
            ax = 0.f; ay = 0.f; cur = r;
        }
        const float2* p = (const float2*)(frf + (size_t)(t0 + k) * DD);
        float2 v = p[tid];
        ax += v.x; ay += v.y;
    }
    float* dst = la + ((size_t)b * LL + cur) * DD + tid * 2;
    atomicAdd(dst, ax);
    atomicAdd(dst + 1, ay);
}

// ---------------- Kernel 5: glc dots per (b,c): tok row staged, 16 dots + ntk ----------------
__global__ __launch_bounds__(256) void k_glc(const float* __restrict__ feat,
                                             const float* __restrict__ la,
                                             float* __restrict__ dots,
                                             float* __restrict__ ntk) {
    int c = blockIdx.x, b = blockIdx.y;
    __shared__ float tok_s[DD];
    __shared__ float redv[4];
    int tid = threadIdx.x;
    int wave = tid >> 6, lane = tid & 63;
    const float* tr = feat + ((size_t)b * (CC + TT) + c) * DD;
    float2 tv = ((const float2*)tr)[tid];
    ((float2*)tok_s)[tid] = tv;
    float vv = tv.x * tv.x + tv.y * tv.y;
    vv = wave_reduce_sum(vv);
    if (lane == 0) redv[wave] = vv;
    __syncthreads();
    if (tid == 0)
        ntk[b * CC + c] = fmaxf(sqrtf(redv[0] + redv[1] + redv[2] + redv[3]), 1e-12f);
    for (int l = wave; l < LL; l += 4) {
        const float4* lar = (const float4*)(la + ((size_t)b * LL + l) * DD);
        const float4* ts = (const float4*)tok_s;
        float dot = 0.f;
        #pragma unroll
        for (int jj = 0; jj < 2; ++jj) {
            int j = lane + jj * 64;
            float4 a = lar[j]; float4 w = ts[j];
            dot += a.x * w.x + a.y * w.y + a.z * w.z + a.w * w.w;
        }
        dot = wave_reduce_sum(dot);
        if (lane == 0) dots[((size_t)b * LL + l) * CC + c] = dot;
    }
}

// ---------------- Kernel 6: per-(b,l) term: nla + logsumexp ----------------
__global__ __launch_bounds__(64) void k_term(const float* __restrict__ la,
                                             const float* __restrict__ dots,
                                             const float* __restrict__ ntk,
                                             const int* __restrict__ labels,
                                             float* __restrict__ terms) {
    int l = blockIdx.x, b = blockIdx.y;
    int lane = threadIdx.x;
    const float4* lar = (const float4*)(la + ((size_t)b * LL + l) * DD);
    float ss = 0.f;
    #pragma unroll
    for (int jj = 0; jj < 2; ++jj) {
        float4 a = lar[lane + jj * 64];
        ss += a.x * a.x + a.y * a.y + a.z * a.z + a.w * a.w;
    }
    ss = wave_reduce_sum(ss);
    float nla = fmaxf(sqrtf(__shfl(ss, 0)), 1e-12f);
    float sim = -INFINITY;
    if (lane < CC)
        sim = dots[((size_t)b * LL + l) * CC + lane] * 10.0f / (nla * ntk[b * CC + lane]);
    float mx = sim;
    for (int off = 32; off; off >>= 1) mx = fmaxf(mx, __shfl_down(mx, off));
    mx = __shfl(mx, 0);
    float e = (lane < CC) ? expf(sim - mx) : 0.f;
    float se = wave_reduce_sum(e);
    se = __shfl(se, 0);
    int lab = labels[b * LL + l];
    float sim_lab = __shfl(sim, lab);
    if (lane == 0) terms[b * LL + l] = (mx + logf(se)) - sim_lab;
}

// ---------------- Kernel 7: combine ----------------
__global__ __launch_bounds__(256) void k_combine(const float* __restrict__ tok_logit,
                                                 const float* __restrict__ vid,
                                                 const float* __restrict__ fr_part,
                                                 const float* __restrict__ terms,
                                                 float* __restrict__ out) {
    int tid = threadIdx.x;
    __shared__ float red[4];
    __shared__ float gterm;
    float acc = 0.f;
    if (tid < BB * CC) {
        float x = tok_logit[tid], y = vid[tid];
        float lsp = fminf(x, 0.f) - log1pf(expf(-fabsf(x)));
        float lsn = fminf(-x, 0.f) - log1pf(expf(-fabsf(x)));
        acc = -(y * lsp + (1.f - y) * lsn);
    }
    float w = wave_reduce_sum(acc);
    if ((tid & 63) == 0) red[tid >> 6] = w;
    // wave 0: glc terms (64 values)
    if (tid < 64) {
        float g = terms[tid];
        g = wave_reduce_sum(g);
        if (tid == 0) gterm = g;
    }
    __syncthreads();
    if (tid == 0) {
        float s_tok = (red[0] + red[1] + red[2] + red[3]) / (float)(BB * CC);
        float sfr = fr_part[0] + fr_part[1] + fr_part[2] + fr_part[3];
        float s_fr = sfr / (float)(BB * TT);
        float glc = gterm / (float)(BB * LL);
        out[0] = s_tok + s_fr + 0.1f * glc;
    }
}

extern "C" void kernel_launch(void* const* d_in, const int* in_sizes, int n_in,
                              void* d_out, int out_size, void* d_ws, size_t ws_size,
                              hipStream_t stream) {
    (void)in_sizes; (void)n_in; (void)out_size; (void)ws_size;
    // input order: epoch, tok_logit, fr_logit, mask, transcript, vid_multi_hot, feat
    const float* tok_logit  = (const float*)d_in[1];
    const float* fr_logit   = (const float*)d_in[2];
    const int*   transcript = (const int*)d_in[4];
    const float* vid        = (const float*)d_in[5];
    const float* feat       = (const float*)d_in[6];

    char* ws = (char*)d_ws;
    float* lse     = (float*)(ws + 0);        // B*T (32768 B)
    float* score   = (float*)(ws + 32768);    // B*T (32768 B)
    float* la      = (float*)(ws + 65536);    // B*L*D (131072 B)
    float* dots    = (float*)(ws + 196608);   // B*L*C (12288 B)
    float* ntk     = (float*)(ws + 208896);   // B*C
    float* terms   = (float*)(ws + 209664);   // B*L
    float* fr_part = (float*)(ws + 209920);   // 4
    int*   labels  = (int*)(ws + 210176);     // B*L
    int*   rowmap  = (int*)(ws + 210432);     // B*T (32768 B)
    float* out     = (float*)d_out;

    k_lse<<<BB * TT / 4, 256, 0, stream>>>(fr_logit, lse);
    k_score<<<BB * TT, 64, 0, stream>>>(fr_logit, lse, score);
    k_pickdp<<<BB, 256, 0, stream>>>(fr_logit, lse, score, transcript,
                                     labels, rowmap, fr_part, la);
    k_la<<<dim3(TT / 32, BB), 256, 0, stream>>>(feat, rowmap, la);
    k_glc<<<dim3(CC, BB), 256, 0, stream>>>(feat, la, dots, ntk);
    k_term<<<dim3(LL, BB), 64, 0, stream>>>(la, dots, ntk, labels, terms);
    k_combine<<<1, 256, 0, stream>>>(tok_logit, vid, fr_part, terms, out);
}